// Round 2
// baseline (11492.365 us; speedup 1.0000x reference)
//
#include <hip/hip_runtime.h>
#include <hip/hip_bf16.h>
#include <math.h>

// SpectralGPT forward pass on MI355X. B=4 T=1024 C=768 NH=12 HS=64 NL=6 VOCAB=128.
// Round 2: correctness-first with runtime input-dtype detection (bf16 vs f32).
// All external float tensors are normalized to bf16 workspace copies by a
// convert kernel (dtype branch on a device flag detected from ln1_g==ones),
// so the main pipeline is dtype-agnostic. fp32 residual stream, bf16
// intermediates, VALU tiled GEMM, per-(b,h,t) attention.

#define Bz 4
#define Tz 1024
#define Cz 768
#define NHz 12
#define HSz 64
#define NLz 6
#define VOCABz 128
#define NTOK (Bz * Tz)  // 4096

typedef __hip_bfloat16 bf16;

__device__ __forceinline__ float bf2f(bf16 x) { return __bfloat162float(x); }
__device__ __forceinline__ bf16 f2bf(float x) { return __float2bfloat16(x); }
__device__ __forceinline__ float us2f(unsigned int s) {
  return __uint_as_float(s << 16);
}

// -------------------------------------------------------------- dtype detect
// ln1_g is all ones. bf16 buffer: every u16 == 0x3F80. f32 buffer: u16 words
// alternate 0x0000, 0x3F80. Count hits in first 64 words.
__global__ void detect_kernel(const void* g1, int* flag) {
  if (threadIdx.x == 0) {
    const unsigned short* p = (const unsigned short*)g1;
    int cnt = 0;
    for (int i = 0; i < 64; i++) cnt += (p[i] == 0x3F80u) ? 1 : 0;
    *flag = (cnt >= 60) ? 1 : 0;
  }
}

// ------------------------------------------------------------- convert->bf16
__global__ __launch_bounds__(256) void convert_kernel(
    const void* __restrict__ src, bf16* __restrict__ dst, int n,
    const int* __restrict__ flagp) {
  int f = *flagp;
  int i = blockIdx.x * 256 + threadIdx.x;
  if (i >= n) return;
  dst[i] = f ? ((const bf16*)src)[i] : f2bf(((const float*)src)[i]);
}

// ---------------------------------------------------------------- embedding
__global__ __launch_bounds__(256) void embed_kernel(
    const int* __restrict__ idx, const bf16* __restrict__ tok_emb,
    const bf16* __restrict__ pe_w, const bf16* __restrict__ pe_b,
    const bf16* __restrict__ vlut, float* __restrict__ x_res) {
  int row = blockIdx.x;  // b*T + t
  int t = row % Tz;
  int tok = idx[row];
  float vl[10];
#pragma unroll
  for (int p = 0; p < 10; p++) vl[p] = bf2f(vlut[t * 10 + p]);
  for (int c = threadIdx.x; c < Cz; c += 256) {
    float acc = bf2f(tok_emb[(size_t)tok * Cz + c]) + bf2f(pe_b[c]);
#pragma unroll
    for (int p = 0; p < 10; p++) acc += vl[p] * bf2f(pe_w[p * Cz + c]);
    x_res[(size_t)row * Cz + c] = acc;
  }
}

// ---------------------------------------------------------------- layernorm
__global__ __launch_bounds__(256) void ln_kernel(
    const float* __restrict__ x, const bf16* __restrict__ g,
    const bf16* __restrict__ b, bf16* __restrict__ out) {
  __shared__ float r1[4], r2[4];
  int row = blockIdx.x, tid = threadIdx.x;
  const float* xr = x + (size_t)row * Cz;
  float v0 = xr[tid], v1 = xr[tid + 256], v2 = xr[tid + 512];
  float s1 = v0 + v1 + v2, s2 = v0 * v0 + v1 * v1 + v2 * v2;
#pragma unroll
  for (int off = 32; off > 0; off >>= 1) {
    s1 += __shfl_down(s1, off);
    s2 += __shfl_down(s2, off);
  }
  int lane = tid & 63, wid = tid >> 6;
  if (lane == 0) { r1[wid] = s1; r2[wid] = s2; }
  __syncthreads();
  s1 = r1[0] + r1[1] + r1[2] + r1[3];
  s2 = r2[0] + r2[1] + r2[2] + r2[3];
  float m = s1 * (1.0f / Cz);
  float var = s2 * (1.0f / Cz) - m * m;
  float inv = rsqrtf(var + 1e-5f);
  bf16* orow = out + (size_t)row * Cz;
  orow[tid] = f2bf((v0 - m) * inv * bf2f(g[tid]) + bf2f(b[tid]));
  orow[tid + 256] = f2bf((v1 - m) * inv * bf2f(g[tid + 256]) + bf2f(b[tid + 256]));
  orow[tid + 512] = f2bf((v2 - m) * inv * bf2f(g[tid + 512]) + bf2f(b[tid + 512]));
}

// ----------------------------------------------------------- qkv weight pack
// wp[l][k][n], n in [0,2304): q|k|v, col n%768 -> (h = /64, d = %64)
// src tensors are already-normalized bf16 copies.
__global__ __launch_bounds__(256) void pack_qkv(
    const bf16* __restrict__ qw, const bf16* __restrict__ kw,
    const bf16* __restrict__ vw, bf16* __restrict__ wp) {
  int i = blockIdx.x * 256 + threadIdx.x;
  const int total = NLz * Cz * 3 * Cz;
  if (i >= total) return;
  int n = i % (3 * Cz);
  int k = (i / (3 * Cz)) % Cz;
  int l = i / (3 * Cz * Cz);
  const bf16* src = (n < Cz) ? qw : (n < 2 * Cz) ? kw : vw;
  int nn = n % Cz;
  int h = nn / HSz, d = nn % HSz;
  wp[i] = src[(((size_t)l * NHz + h) * Cz + k) * HSz + d];
}

// ---------------------------------------------------------------- GEMM
// C[M,N] = A[M,K](bf16,rowmajor) x W[K,N](bf16,rowmajor) + bias
// mode 0: out=bf16(r)  mode 1: out=bf16(gelu(r))  mode 2: resid += r
// mode 3: head output -> bf16 or f32 per *flagp
#define BM 64
#define BN 64
#define BK 16
__global__ __launch_bounds__(256) void gemm_kernel(
    const bf16* __restrict__ A, const bf16* __restrict__ W,
    const bf16* __restrict__ bias, float* __restrict__ resid,
    void* __restrict__ out, int M, int N, int K, int mode,
    const int* __restrict__ flagp) {
  __shared__ float As[BK][BM];  // transposed store: As[k][m]
  __shared__ float Ws[BK][BN];
  int tid = threadIdx.x;
  int n0 = blockIdx.x * BN;
  int m0 = blockIdx.y * BM;
  int tx = tid & 15, ty = tid >> 4;
  int ar = tid >> 2, ac = (tid & 3) * 4;
  int wr = tid >> 4, wc = (tid & 15) * 4;
  float acc[4][4] = {};
  for (int k0 = 0; k0 < K; k0 += BK) {
    ushort4 av = *(const ushort4*)(A + (size_t)(m0 + ar) * K + k0 + ac);
    ushort4 wv = *(const ushort4*)(W + (size_t)(k0 + wr) * N + n0 + wc);
    __syncthreads();  // previous compute done before overwrite
    As[ac + 0][ar] = us2f(av.x & 0xffffu);
    As[ac + 1][ar] = us2f(av.y & 0xffffu);
    As[ac + 2][ar] = us2f(av.z & 0xffffu);
    As[ac + 3][ar] = us2f(av.w & 0xffffu);
    *(float4*)&Ws[wr][wc] = make_float4(us2f(wv.x & 0xffffu), us2f(wv.y & 0xffffu),
                                        us2f(wv.z & 0xffffu), us2f(wv.w & 0xffffu));
    __syncthreads();
#pragma unroll
    for (int kk = 0; kk < BK; kk++) {
      float4 a4 = *(const float4*)&As[kk][ty * 4];
      float4 b4 = *(const float4*)&Ws[kk][tx * 4];
      float a[4] = {a4.x, a4.y, a4.z, a4.w};
      float bb[4] = {b4.x, b4.y, b4.z, b4.w};
#pragma unroll
      for (int i = 0; i < 4; i++)
#pragma unroll
        for (int j = 0; j < 4; j++) acc[i][j] += a[i] * bb[j];
    }
  }
#pragma unroll
  for (int i = 0; i < 4; i++) {
    int m = m0 + ty * 4 + i;
#pragma unroll
    for (int j = 0; j < 4; j++) {
      int n = n0 + tx * 4 + j;
      float r = acc[i][j] + (bias ? bf2f(bias[n]) : 0.0f);
      size_t oi = (size_t)m * N + n;
      if (mode == 0) {
        ((bf16*)out)[oi] = f2bf(r);
      } else if (mode == 1) {
        ((bf16*)out)[oi] = f2bf(r * 0.5f * (1.0f + erff(r * 0.70710678118f)));
      } else if (mode == 2) {
        resid[oi] += r;
      } else {
        if (*flagp) ((bf16*)out)[oi] = f2bf(r);
        else ((float*)out)[oi] = r;
      }
    }
  }
}

// ---------------------------------------------------------------- attention
// one block per (b,h,t); qkv rows: [q(768) k(768) v(768)].
// allowed(t,s) == (s<=t) && (rbias>0 || s==t)  -- exact reconstruction:
// rbias = log1p(res)*allowed, res integer >=0, diag always allowed & causal.
__global__ __launch_bounds__(256) void attn_kernel(
    const bf16* __restrict__ qkv, const bf16* __restrict__ rbias,
    bf16* __restrict__ attn_out) {
  __shared__ float sc[Tz];
  __shared__ float qs[HSz];
  __shared__ float red[4];
  __shared__ float ored[4][HSz];
  int tid = threadIdx.x;
  int t = blockIdx.x % Tz;
  int h = (blockIdx.x / Tz) % NHz;
  int b = blockIdx.x / (Tz * NHz);
  const size_t rs = 3 * Cz;
  const bf16* qrow = qkv + ((size_t)(b * Tz + t)) * rs + h * HSz;
  if (tid < HSz) qs[tid] = bf2f(qrow[tid]);
  __syncthreads();
  const float scale = 0.03608439182435161f;  // 1/sqrt(768): scale = C^-0.5

  const bf16* kbase = qkv + (size_t)b * Tz * rs + Cz + h * HSz;
  for (int s = tid; s <= t; s += 256) {
    const uint4* k4 = (const uint4*)(kbase + (size_t)s * rs);
    float acc = 0.0f;
#pragma unroll
    for (int i = 0; i < 8; i++) {
      uint4 u = k4[i];
      acc += qs[8 * i + 0] * us2f(u.x & 0xffffu);
      acc += qs[8 * i + 1] * us2f(u.x >> 16);
      acc += qs[8 * i + 2] * us2f(u.y & 0xffffu);
      acc += qs[8 * i + 3] * us2f(u.y >> 16);
      acc += qs[8 * i + 4] * us2f(u.z & 0xffffu);
      acc += qs[8 * i + 5] * us2f(u.z >> 16);
      acc += qs[8 * i + 6] * us2f(u.w & 0xffffu);
      acc += qs[8 * i + 7] * us2f(u.w >> 16);
    }
    float rb = bf2f(rbias[(size_t)t * Tz + s]);
    sc[s] = ((rb > 0.0f) || (s == t)) ? (acc * scale + rb) : -3.4e38f;
  }
  __syncthreads();
  float mx = -3.4e38f;
  for (int s = tid; s <= t; s += 256) mx = fmaxf(mx, sc[s]);
#pragma unroll
  for (int off = 32; off > 0; off >>= 1) mx = fmaxf(mx, __shfl_down(mx, off));
  int lane = tid & 63, wid = tid >> 6;
  if (lane == 0) red[wid] = mx;
  __syncthreads();
  mx = fmaxf(fmaxf(red[0], red[1]), fmaxf(red[2], red[3]));
  float sum = 0.0f;
  for (int s = tid; s <= t; s += 256) {
    float p = expf(sc[s] - mx);
    sc[s] = p;
    sum += p;
  }
  __syncthreads();
#pragma unroll
  for (int off = 32; off > 0; off >>= 1) sum += __shfl_down(sum, off);
  if (lane == 0) red[wid] = sum;
  __syncthreads();
  sum = red[0] + red[1] + red[2] + red[3];
  int g = tid >> 6, d = tid & 63;
  const bf16* vbase = qkv + (size_t)b * Tz * rs + 2 * Cz + h * HSz + d;
  float acc = 0.0f;
  for (int s = g; s <= t; s += 4) acc += sc[s] * bf2f(vbase[(size_t)s * rs]);
  ored[g][d] = acc;
  __syncthreads();
  if (tid < HSz) {
    float o = (ored[0][tid] + ored[1][tid] + ored[2][tid] + ored[3][tid]) / sum;
    attn_out[(size_t)(b * Tz + t) * Cz + h * HSz + tid] = f2bf(o);
  }
}

// ---------------------------------------------------------------- launcher
extern "C" void kernel_launch(void* const* d_in, const int* in_sizes, int n_in,
                              void* d_out, int out_size, void* d_ws, size_t ws_size,
                              hipStream_t stream) {
  const int* idx = (const int*)d_in[0];
  // 'allowed' (bool) may or may not occupy slot 6; detect via n_in / sizes.
  int p0 = 7;
  if (n_in == 23) p0 = 6;                  // allowed not passed at all
  else if (in_sizes[6] != Tz * Tz) p0 = 6; // slot 6 is already ln1_g

  // raw (unknown-dtype) external pointers, in order:
  // tok_emb pe_w pe_b vlut rbias | ln1_g ln1_b qw kw vw proj_w proj_b
  // ln2_g ln2_b ff1_w ff1_b ff2_w ff2_b lnf_g lnf_b head_w head_b
  const void* raw[22];
  const int rawsz[22] = {
      VOCABz * Cz, 10 * Cz, Cz, Tz * 10, Tz * Tz,
      NLz * Cz, NLz * Cz,
      NLz * NHz * Cz * HSz, NLz * NHz * Cz * HSz, NLz * NHz * Cz * HSz,
      NLz * Cz * Cz, NLz * Cz,
      NLz * Cz, NLz * Cz,
      NLz * Cz * 4 * Cz, NLz * 4 * Cz,
      NLz * 4 * Cz * Cz, NLz * Cz,
      Cz, Cz, Cz * VOCABz, VOCABz};
  raw[0] = d_in[1]; raw[1] = d_in[2]; raw[2] = d_in[3]; raw[3] = d_in[4];
  raw[4] = d_in[5];
  for (int i = 0; i < 17; i++) raw[5 + i] = d_in[p0 + i];

  // ------------------------------------------------- workspace layout
  char* w = (char*)d_ws;
  int* flag = (int*)w;           w += 256;
  float* x_res = (float*)w;      w += (size_t)NTOK * Cz * 4;         // 12.58 MB
  bf16* h = (bf16*)w;            w += (size_t)NTOK * Cz * 2;         //  6.29 MB
  bf16* qkv = (bf16*)w;          w += (size_t)NTOK * 3 * Cz * 2;     // 18.87 MB
  bf16* attn = (bf16*)w;         w += (size_t)NTOK * Cz * 2;         //  6.29 MB
  bf16* ffm = (bf16*)w;          w += (size_t)NTOK * 4 * Cz * 2;     // 25.17 MB
  bf16* wqkv = (bf16*)w;         w += (size_t)NLz * Cz * 3 * Cz * 2; // 21.23 MB
  // normalized bf16 copies of all external float tensors (~85 MB)
  bf16* nrm[22];
  for (int i = 0; i < 22; i++) {
    nrm[i] = (bf16*)w;
    w += ((size_t)rawsz[i] * 2 + 255) & ~(size_t)255;
  }

  const bf16* tok_emb = nrm[0];
  const bf16* pe_w = nrm[1];
  const bf16* pe_b = nrm[2];
  const bf16* vlut = nrm[3];
  const bf16* rbias = nrm[4];
  const bf16* ln1_g = nrm[5];
  const bf16* ln1_b = nrm[6];
  const bf16* qw = nrm[7];
  const bf16* kw = nrm[8];
  const bf16* vw = nrm[9];
  const bf16* proj_w = nrm[10];
  const bf16* proj_b = nrm[11];
  const bf16* ln2_g = nrm[12];
  const bf16* ln2_b = nrm[13];
  const bf16* ff1_w = nrm[14];
  const bf16* ff1_b = nrm[15];
  const bf16* ff2_w = nrm[16];
  const bf16* ff2_b = nrm[17];
  const bf16* lnf_g = nrm[18];
  const bf16* lnf_b = nrm[19];
  const bf16* head_w = nrm[20];
  const bf16* head_b = nrm[21];

  // ------------------------------------------------- normalize + pack
  detect_kernel<<<1, 64, 0, stream>>>(raw[5] /*ln1_g*/, flag);
  for (int i = 0; i < 22; i++) {
    convert_kernel<<<(rawsz[i] + 255) / 256, 256, 0, stream>>>(
        raw[i], nrm[i], rawsz[i], flag);
  }
  pack_qkv<<<(NLz * Cz * 3 * Cz + 255) / 256, 256, 0, stream>>>(qw, kw, vw, wqkv);
  embed_kernel<<<NTOK, 256, 0, stream>>>(idx, tok_emb, pe_w, pe_b, vlut, x_res);

  // ------------------------------------------------- transformer layers
  for (int l = 0; l < NLz; l++) {
    ln_kernel<<<NTOK, 256, 0, stream>>>(x_res, ln1_g + l * Cz, ln1_b + l * Cz, h);
    gemm_kernel<<<dim3(2304 / BN, NTOK / BM), 256, 0, stream>>>(
        h, wqkv + (size_t)l * Cz * 3 * Cz, nullptr, nullptr, qkv,
        NTOK, 3 * Cz, Cz, 0, flag);
    attn_kernel<<<Bz * NHz * Tz, 256, 0, stream>>>(qkv, rbias, attn);
    gemm_kernel<<<dim3(Cz / BN, NTOK / BM), 256, 0, stream>>>(
        attn, proj_w + (size_t)l * Cz * Cz, proj_b + l * Cz, x_res, nullptr,
        NTOK, Cz, Cz, 2, flag);
    ln_kernel<<<NTOK, 256, 0, stream>>>(x_res, ln2_g + l * Cz, ln2_b + l * Cz, h);
    gemm_kernel<<<dim3(4 * Cz / BN, NTOK / BM), 256, 0, stream>>>(
        h, ff1_w + (size_t)l * Cz * 4 * Cz, ff1_b + (size_t)l * 4 * Cz, nullptr,
        ffm, NTOK, 4 * Cz, Cz, 1, flag);
    gemm_kernel<<<dim3(Cz / BN, NTOK / BM), 256, 0, stream>>>(
        ffm, ff2_w + (size_t)l * 4 * Cz * Cz, ff2_b + l * Cz, x_res, nullptr,
        NTOK, Cz, 4 * Cz, 2, flag);
  }
  ln_kernel<<<NTOK, 256, 0, stream>>>(x_res, lnf_g, lnf_b, h);
  gemm_kernel<<<dim3(VOCABz / BN, NTOK / BM), 256, 0, stream>>>(
      h, head_w, head_b, nullptr, d_out, NTOK, VOCABz, Cz, 3, flag);
}

// Round 3
// 2297.908 us; speedup vs baseline: 5.0012x; 5.0012x over previous
//
#include <hip/hip_runtime.h>
#include <hip/hip_bf16.h>
#include <math.h>

// SpectralGPT forward on MI355X. B=4 T=1024 C=768 NH=12 HS=64 NL=6 VOCAB=128.
// Round 3: MFMA everywhere. Weights pre-transposed to [N][K] (setup kernels),
// 128x128-tile MFMA GEMM with fused epilogues, flash-style MFMA attention
// (online softmax, P->A-layout via LDS round trip, V pre-transposed to [d][s]).
// fp32 residual stream; bf16 activations; runtime input-dtype detect kept.

#define Bz 4
#define Tz 1024
#define Cz 768
#define NHz 12
#define HSz 64
#define NLz 6
#define VOCABz 128
#define NTOK (Bz * Tz)  // 4096

typedef __hip_bfloat16 bf16;
typedef __attribute__((ext_vector_type(8))) __bf16 bf16x8;
typedef __attribute__((ext_vector_type(4))) float f32x4;

#define MFMA16(a, b, c) __builtin_amdgcn_mfma_f32_16x16x32_bf16(a, b, c, 0, 0, 0)

__device__ __forceinline__ float bf2f(bf16 x) { return __bfloat162float(x); }
__device__ __forceinline__ bf16 f2bf(float x) { return __float2bfloat16(x); }
// external input load: f==1 -> bf16, f==0 -> float32
__device__ __forceinline__ float ldx(const void* p, size_t i, int f) {
  return f ? bf2f(((const bf16*)p)[i]) : ((const float*)p)[i];
}

// -------------------------------------------------------------- dtype detect
__global__ void detect_kernel(const void* g1, int* flag) {
  if (threadIdx.x == 0) {
    const unsigned short* p = (const unsigned short*)g1;
    int cnt = 0;
    for (int i = 0; i < 64; i++) cnt += (p[i] == 0x3F80u) ? 1 : 0;
    *flag = (cnt >= 60) ? 1 : 0;
  }
}

// ------------------------------------------------------------- convert->bf16
__global__ __launch_bounds__(256) void convert_kernel(
    const void* __restrict__ src, bf16* __restrict__ dst, int n,
    const int* __restrict__ flagp) {
  int f = *flagp;
  int i = blockIdx.x * 256 + threadIdx.x;
  if (i >= n) return;
  dst[i] = f ? ((const bf16*)src)[i] : f2bf(((const float*)src)[i]);
}

// ----------------------------------------------- weight transpose: dst[l][n][k]
__global__ __launch_bounds__(256) void transpose_w(
    const void* __restrict__ src, bf16* __restrict__ dst, int L, int K, int N,
    const int* __restrict__ flagp) {
  int f = *flagp;
  size_t i = (size_t)blockIdx.x * 256 + threadIdx.x;
  size_t total = (size_t)L * K * N;
  if (i >= total) return;
  int k = i % K;
  size_t r = i / K;
  int n = r % N;
  int l = r / N;
  dst[i] = f2bf(ldx(src, ((size_t)l * K + k) * N + n, f));
}

// ------------------------------------- qkv weight pack+transpose: [l][2304][768]
// n<768: q, n<1536: k, else v. within group: h=nn/64, d=nn%64.
// src [l][h][c=k][d] -> idx (((l*12+h)*768 + k)*64 + d)
__global__ __launch_bounds__(256) void pack_qkv_t(
    const void* __restrict__ qw, const void* __restrict__ kw,
    const void* __restrict__ vw, bf16* __restrict__ dst,
    const int* __restrict__ flagp) {
  int f = *flagp;
  size_t i = (size_t)blockIdx.x * 256 + threadIdx.x;
  const size_t total = (size_t)NLz * 3 * Cz * Cz;
  if (i >= total) return;
  int k = i % Cz;
  size_t r = i / Cz;
  int n = r % (3 * Cz);
  int l = r / (3 * Cz);
  const void* src = (n < Cz) ? qw : (n < 2 * Cz) ? kw : vw;
  int nn = n % Cz;
  int h = nn / HSz, d = nn % HSz;
  dst[i] = f2bf(ldx(src, (((size_t)l * NHz + h) * Cz + k) * HSz + d, f));
}

// ---------------------------------------------------------------- embedding
__global__ __launch_bounds__(256) void embed_kernel(
    const int* __restrict__ idx, const bf16* __restrict__ tok_emb,
    const bf16* __restrict__ pe_w, const bf16* __restrict__ pe_b,
    const bf16* __restrict__ vlut, float* __restrict__ x_res) {
  int row = blockIdx.x;
  int t = row % Tz;
  int tok = idx[row];
  float vl[10];
#pragma unroll
  for (int p = 0; p < 10; p++) vl[p] = bf2f(vlut[t * 10 + p]);
  for (int c = threadIdx.x; c < Cz; c += 256) {
    float acc = bf2f(tok_emb[(size_t)tok * Cz + c]) + bf2f(pe_b[c]);
#pragma unroll
    for (int p = 0; p < 10; p++) acc += vl[p] * bf2f(pe_w[p * Cz + c]);
    x_res[(size_t)row * Cz + c] = acc;
  }
}

// ---------------------------------------------------------------- layernorm
__global__ __launch_bounds__(256) void ln_kernel(
    const float* __restrict__ x, const bf16* __restrict__ g,
    const bf16* __restrict__ b, bf16* __restrict__ out) {
  __shared__ float r1[4], r2[4];
  int row = blockIdx.x, tid = threadIdx.x;
  const float* xr = x + (size_t)row * Cz;
  float v0 = xr[tid], v1 = xr[tid + 256], v2 = xr[tid + 512];
  float s1 = v0 + v1 + v2, s2 = v0 * v0 + v1 * v1 + v2 * v2;
#pragma unroll
  for (int off = 32; off > 0; off >>= 1) {
    s1 += __shfl_down(s1, off);
    s2 += __shfl_down(s2, off);
  }
  int lane = tid & 63, wid = tid >> 6;
  if (lane == 0) { r1[wid] = s1; r2[wid] = s2; }
  __syncthreads();
  s1 = r1[0] + r1[1] + r1[2] + r1[3];
  s2 = r2[0] + r2[1] + r2[2] + r2[3];
  float m = s1 * (1.0f / Cz);
  float var = s2 * (1.0f / Cz) - m * m;
  float inv = rsqrtf(var + 1e-5f);
  bf16* orow = out + (size_t)row * Cz;
  orow[tid] = f2bf((v0 - m) * inv * bf2f(g[tid]) + bf2f(b[tid]));
  orow[tid + 256] = f2bf((v1 - m) * inv * bf2f(g[tid + 256]) + bf2f(b[tid + 256]));
  orow[tid + 512] = f2bf((v2 - m) * inv * bf2f(g[tid + 512]) + bf2f(b[tid + 512]));
}

// ---------------------------------------------------------------- MFMA GEMM
// C[M,N] = A[M,K](bf16 rowmajor) x W (bf16, PRE-TRANSPOSED [N][K]) + bias
// 128x128 tile, BK=32, 4 waves in 2x2, each wave 64x64 via 4x4 16x16x32 MFMAs.
// mode 0: out=bf16(r)  1: out=bf16(gelu(r))  2: resid += r  3: per-flag dtype out
#define LDK 40  // 32 + 8 pad (2-way LDS banking, 16B-aligned rows: 80B)
__global__ __launch_bounds__(256) void gemm_mfma(
    const bf16* __restrict__ A, const bf16* __restrict__ Wt,
    const bf16* __restrict__ bias, float* __restrict__ resid,
    void* __restrict__ out, int M, int N, int K, int mode,
    const int* __restrict__ flagp) {
  __shared__ bf16 As[128][LDK];
  __shared__ bf16 Bs[128][LDK];
  int tid = threadIdx.x;
  int lane = tid & 63, w = tid >> 6;
  int wm = (w >> 1) * 64, wn = (w & 1) * 64;
  int q = lane >> 4, ln = lane & 15;
  int m0 = blockIdx.y * 128, n0 = blockIdx.x * 128;
  int srow = tid >> 1, scol = (tid & 1) * 16;
  const bf16* Ap = A + (size_t)(m0 + srow) * K + scol;
  const bf16* Bp = Wt + (size_t)(n0 + srow) * K + scol;
  f32x4 acc[4][4] = {};
  for (int k0 = 0; k0 < K; k0 += 32) {
    uint4 a0 = *(const uint4*)(Ap + k0);
    uint4 a1 = *(const uint4*)(Ap + k0 + 8);
    uint4 b0 = *(const uint4*)(Bp + k0);
    uint4 b1 = *(const uint4*)(Bp + k0 + 8);
    __syncthreads();
    *(uint4*)&As[srow][scol] = a0;
    *(uint4*)&As[srow][scol + 8] = a1;
    *(uint4*)&Bs[srow][scol] = b0;
    *(uint4*)&Bs[srow][scol + 8] = b1;
    __syncthreads();
    bf16x8 af[4], bfr[4];
#pragma unroll
    for (int i = 0; i < 4; i++)
      af[i] = *(const bf16x8*)&As[wm + i * 16 + ln][q * 8];
#pragma unroll
    for (int j = 0; j < 4; j++)
      bfr[j] = *(const bf16x8*)&Bs[wn + j * 16 + ln][q * 8];
#pragma unroll
    for (int i = 0; i < 4; i++)
#pragma unroll
      for (int j = 0; j < 4; j++)
        acc[i][j] = MFMA16(af[i], bfr[j], acc[i][j]);
  }
  int f = *flagp;
  float bj[4];
#pragma unroll
  for (int j = 0; j < 4; j++)
    bj[j] = bias ? bf2f(bias[n0 + wn + j * 16 + ln]) : 0.0f;
#pragma unroll
  for (int i = 0; i < 4; i++) {
#pragma unroll
    for (int j = 0; j < 4; j++) {
      int col = n0 + wn + j * 16 + ln;
#pragma unroll
      for (int r = 0; r < 4; r++) {
        int row = m0 + wm + i * 16 + q * 4 + r;
        float v = acc[i][j][r] + bj[j];
        size_t oi = (size_t)row * N + col;
        if (mode == 0) {
          ((bf16*)out)[oi] = f2bf(v);
        } else if (mode == 1) {
          ((bf16*)out)[oi] = f2bf(v * 0.5f * (1.0f + erff(v * 0.70710678118f)));
        } else if (mode == 2) {
          resid[oi] += v;
        } else {
          if (f) ((bf16*)out)[oi] = f2bf(v);
          else ((float*)out)[oi] = v;
        }
      }
    }
  }
}

// --------------------------------------------- V transpose: qkv -> Vt[bh][d][s]
#define ATS 72  // 64 + 8 pad (rows 144B, 16B aligned)
__global__ __launch_bounds__(256) void transpose_v(
    const bf16* __restrict__ qkv, bf16* __restrict__ Vt) {
  __shared__ bf16 tile[64][ATS];
  int tid = threadIdx.x;
  int s0 = blockIdx.x * 64, bh = blockIdx.y;
  int b = bh / NHz, h = bh % NHz;
  int row = tid >> 2, c0 = (tid & 3) * 16;
  const bf16* src = qkv + ((size_t)(b * Tz + s0 + row)) * (3 * Cz) + 2 * Cz + h * HSz + c0;
  *(uint4*)&tile[row][c0] = *(const uint4*)src;
  *(uint4*)&tile[row][c0 + 8] = *(const uint4*)(src + 8);
  __syncthreads();
  int d = tid >> 2, sc0 = (tid & 3) * 16;
  unsigned int u[8];
#pragma unroll
  for (int m = 0; m < 8; m++) {
    unsigned int lo = *(const unsigned short*)&tile[sc0 + 2 * m][d];
    unsigned int hi = *(const unsigned short*)&tile[sc0 + 2 * m + 1][d];
    u[m] = lo | (hi << 16);
  }
  bf16* dst = Vt + ((size_t)bh * HSz + d) * Tz + s0 + sc0;
  ((uint4*)dst)[0] = make_uint4(u[0], u[1], u[2], u[3]);
  ((uint4*)dst)[1] = make_uint4(u[4], u[5], u[6], u[7]);
}

// ------------------------------------------------------- flash MFMA attention
// block = (t-tile of 64, bh). 4 waves; wave w owns t rows [t0+16w, +16).
// S = Q K^T * scale + rbias, masked; online softmax; O += P V.
// allowed(t,s) == (s<=t) && (rbias>0 || s==t).
__global__ __launch_bounds__(256) void attn_flash(
    const bf16* __restrict__ qkv, const bf16* __restrict__ Vt,
    const bf16* __restrict__ rbias, bf16* __restrict__ attn_out) {
  __shared__ bf16 Qs[64][ATS];
  __shared__ bf16 Ks[64][ATS];
  __shared__ bf16 Vs[64][ATS];
  __shared__ bf16 Ps[4][16][ATS];
  int tid = threadIdx.x;
  int lane = tid & 63, w = tid >> 6;
  int q = lane >> 4, ln = lane & 15;
  int t0 = blockIdx.x * 64, bh = blockIdx.y;
  int b = bh / NHz, h = bh % NHz;
  const float scale = 0.03608439182435161f;  // C^-0.5 = 1/sqrt(768)
  int srow = tid >> 2, sc = (tid & 3) * 16;
  // stage Q tile
  {
    const bf16* src = qkv + ((size_t)(b * Tz + t0 + srow)) * (3 * Cz) + h * HSz + sc;
    *(uint4*)&Qs[srow][sc] = *(const uint4*)src;
    *(uint4*)&Qs[srow][sc + 8] = *(const uint4*)(src + 8);
  }
  float mrow[4], lrow[4];
  f32x4 Oacc[4] = {};
#pragma unroll
  for (int r = 0; r < 4; r++) { mrow[r] = -3.0e38f; lrow[r] = 0.0f; }
  int t_base = t0 + w * 16 + q * 4;

  for (int s0 = 0; s0 <= t0 + 63; s0 += 64) {
    __syncthreads();  // waves done with previous Ks/Vs
    {
      const bf16* ksrc = qkv + ((size_t)(b * Tz + s0 + srow)) * (3 * Cz) + Cz + h * HSz + sc;
      *(uint4*)&Ks[srow][sc] = *(const uint4*)ksrc;
      *(uint4*)&Ks[srow][sc + 8] = *(const uint4*)(ksrc + 8);
      const bf16* vsrc = Vt + ((size_t)bh * HSz + srow) * Tz + s0 + sc;
      *(uint4*)&Vs[srow][sc] = *(const uint4*)vsrc;
      *(uint4*)&Vs[srow][sc + 8] = *(const uint4*)(vsrc + 8);
    }
    __syncthreads();
    // ---- S = Q K^T
    f32x4 sacc[4] = {};
#pragma unroll
    for (int ks = 0; ks < 64; ks += 32) {
      bf16x8 aq = *(const bf16x8*)&Qs[w * 16 + ln][ks + q * 8];
#pragma unroll
      for (int j = 0; j < 4; j++) {
        bf16x8 bk = *(const bf16x8*)&Ks[j * 16 + ln][ks + q * 8];
        sacc[j] = MFMA16(aq, bk, sacc[j]);
      }
    }
    // ---- mask + rbias
    float sval[4][4];
#pragma unroll
    for (int j = 0; j < 4; j++) {
      int s_col = s0 + j * 16 + ln;
#pragma unroll
      for (int r = 0; r < 4; r++) {
        int t_row = t_base + r;
        float rb = bf2f(rbias[(size_t)t_row * Tz + s_col]);
        float v = sacc[j][r] * scale + rb;
        bool ok = (s_col <= t_row) && ((rb > 0.0f) || (s_col == t_row));
        sval[j][r] = ok ? v : -3.0e38f;
      }
    }
    // ---- row max (over 4 j and 16 lanes of the quad)
    float rmax[4];
#pragma unroll
    for (int r = 0; r < 4; r++)
      rmax[r] = fmaxf(fmaxf(sval[0][r], sval[1][r]), fmaxf(sval[2][r], sval[3][r]));
#pragma unroll
    for (int msk = 8; msk >= 1; msk >>= 1)
#pragma unroll
      for (int r = 0; r < 4; r++)
        rmax[r] = fmaxf(rmax[r], __shfl_xor(rmax[r], msk));
    float nm[4], nme[4], alpha[4];
#pragma unroll
    for (int r = 0; r < 4; r++) {
      nm[r] = fmaxf(mrow[r], rmax[r]);
      nme[r] = (nm[r] < -1.0e37f) ? 0.0f : nm[r];
      alpha[r] = (mrow[r] < -1.0e37f) ? 0.0f : __expf(mrow[r] - nm[r]);
      mrow[r] = nm[r];
    }
    // ---- P = exp(S - m), row sums
    float pf[4][4];
    float psum[4] = {0.f, 0.f, 0.f, 0.f};
#pragma unroll
    for (int j = 0; j < 4; j++)
#pragma unroll
      for (int r = 0; r < 4; r++) {
        float p = __expf(sval[j][r] - nme[r]);
        pf[j][r] = p;
        psum[r] += p;
      }
#pragma unroll
    for (int msk = 8; msk >= 1; msk >>= 1)
#pragma unroll
      for (int r = 0; r < 4; r++) psum[r] += __shfl_xor(psum[r], msk);
#pragma unroll
    for (int r = 0; r < 4; r++) lrow[r] = alpha[r] * lrow[r] + psum[r];
    // ---- rescale O
#pragma unroll
    for (int jd = 0; jd < 4; jd++)
#pragma unroll
      for (int r = 0; r < 4; r++) Oacc[jd][r] *= alpha[r];
    // ---- P -> LDS (D-layout -> A-layout round trip)
#pragma unroll
    for (int j = 0; j < 4; j++)
#pragma unroll
      for (int r = 0; r < 4; r++)
        Ps[w][q * 4 + r][j * 16 + ln] = f2bf(pf[j][r]);
    // (same-wave LDS producer/consumer; compiler inserts lgkmcnt waits)
    // ---- O += P V
#pragma unroll
    for (int ks = 0; ks < 64; ks += 32) {
      bf16x8 pa = *(const bf16x8*)&Ps[w][ln][ks + q * 8];
#pragma unroll
      for (int jd = 0; jd < 4; jd++) {
        bf16x8 vb = *(const bf16x8*)&Vs[jd * 16 + ln][ks + q * 8];
        Oacc[jd] = MFMA16(pa, vb, Oacc[jd]);
      }
    }
  }
  // ---- write O / l
#pragma unroll
  for (int r = 0; r < 4; r++) {
    float inv = 1.0f / lrow[r];
    int t_row = t_base + r;
#pragma unroll
    for (int jd = 0; jd < 4; jd++) {
      attn_out[(size_t)(b * Tz + t_row) * Cz + h * HSz + jd * 16 + ln] =
          f2bf(Oacc[jd][r] * inv);
    }
  }
}

// ---------------------------------------------------------------- launcher
extern "C" void kernel_launch(void* const* d_in, const int* in_sizes, int n_in,
                              void* d_out, int out_size, void* d_ws, size_t ws_size,
                              hipStream_t stream) {
  const int* idx = (const int*)d_in[0];
  int p0 = 7;
  if (n_in == 23) p0 = 6;
  else if (in_sizes[6] != Tz * Tz) p0 = 6;

  const void* r_tok_emb = d_in[1];
  const void* r_pe_w = d_in[2];
  const void* r_pe_b = d_in[3];
  const void* r_vlut = d_in[4];
  const void* r_rbias = d_in[5];
  const void* r_ln1_g = d_in[p0 + 0];
  const void* r_ln1_b = d_in[p0 + 1];
  const void* r_qw = d_in[p0 + 2];
  const void* r_kw = d_in[p0 + 3];
  const void* r_vw = d_in[p0 + 4];
  const void* r_proj_w = d_in[p0 + 5];
  const void* r_proj_b = d_in[p0 + 6];
  const void* r_ln2_g = d_in[p0 + 7];
  const void* r_ln2_b = d_in[p0 + 8];
  const void* r_ff1_w = d_in[p0 + 9];
  const void* r_ff1_b = d_in[p0 + 10];
  const void* r_ff2_w = d_in[p0 + 11];
  const void* r_ff2_b = d_in[p0 + 12];
  const void* r_lnf_g = d_in[p0 + 13];
  const void* r_lnf_b = d_in[p0 + 14];
  const void* r_head_w = d_in[p0 + 15];
  const void* r_head_b = d_in[p0 + 16];

  // ------------------------------------------------- workspace layout
  char* wsp = (char*)d_ws;
  auto alloc = [&](size_t bytes) {
    char* p = wsp;
    wsp += (bytes + 255) & ~(size_t)255;
    return (void*)p;
  };
  int* flag = (int*)alloc(256);
  float* x_res = (float*)alloc((size_t)NTOK * Cz * 4);
  bf16* h = (bf16*)alloc((size_t)NTOK * Cz * 2);
  bf16* qkv = (bf16*)alloc((size_t)NTOK * 3 * Cz * 2);
  bf16* attn = (bf16*)alloc((size_t)NTOK * Cz * 2);
  bf16* ffm = (bf16*)alloc((size_t)NTOK * 4 * Cz * 2);
  bf16* Vt = (bf16*)alloc((size_t)Bz * NHz * HSz * Tz * 2);
  bf16* wqkv_t = (bf16*)alloc((size_t)NLz * 3 * Cz * Cz * 2);
  bf16* proj_t = (bf16*)alloc((size_t)NLz * Cz * Cz * 2);
  bf16* ff1_t = (bf16*)alloc((size_t)NLz * 4 * Cz * Cz * 2);
  bf16* ff2_t = (bf16*)alloc((size_t)NLz * 4 * Cz * Cz * 2);
  bf16* head_t = (bf16*)alloc((size_t)VOCABz * Cz * 2);
  // small bf16-normalized tensors
  bf16* tok_emb = (bf16*)alloc((size_t)VOCABz * Cz * 2);
  bf16* pe_w = (bf16*)alloc(10 * Cz * 2);
  bf16* pe_b = (bf16*)alloc(Cz * 2);
  bf16* vlut = (bf16*)alloc(Tz * 10 * 2);
  bf16* rbias = (bf16*)alloc((size_t)Tz * Tz * 2);
  bf16* ln1_g = (bf16*)alloc(NLz * Cz * 2);
  bf16* ln1_b = (bf16*)alloc(NLz * Cz * 2);
  bf16* proj_b = (bf16*)alloc(NLz * Cz * 2);
  bf16* ln2_g = (bf16*)alloc(NLz * Cz * 2);
  bf16* ln2_b = (bf16*)alloc(NLz * Cz * 2);
  bf16* ff1_b = (bf16*)alloc(NLz * 4 * Cz * 2);
  bf16* ff2_b = (bf16*)alloc(NLz * Cz * 2);
  bf16* lnf_g = (bf16*)alloc(Cz * 2);
  bf16* lnf_b = (bf16*)alloc(Cz * 2);
  bf16* head_b = (bf16*)alloc(VOCABz * 2);

  detect_kernel<<<1, 64, 0, stream>>>(r_ln1_g, flag);

#define CONV(src, dst, n) \
  convert_kernel<<<((n) + 255) / 256, 256, 0, stream>>>(src, dst, n, flag)
  CONV(r_tok_emb, tok_emb, VOCABz * Cz);
  CONV(r_pe_w, pe_w, 10 * Cz);
  CONV(r_pe_b, pe_b, Cz);
  CONV(r_vlut, vlut, Tz * 10);
  CONV(r_rbias, rbias, Tz * Tz);
  CONV(r_ln1_g, ln1_g, NLz * Cz);
  CONV(r_ln1_b, ln1_b, NLz * Cz);
  CONV(r_proj_b, proj_b, NLz * Cz);
  CONV(r_ln2_g, ln2_g, NLz * Cz);
  CONV(r_ln2_b, ln2_b, NLz * Cz);
  CONV(r_ff1_b, ff1_b, NLz * 4 * Cz);
  CONV(r_ff2_b, ff2_b, NLz * Cz);
  CONV(r_lnf_g, lnf_g, Cz);
  CONV(r_lnf_b, lnf_b, Cz);
  CONV(r_head_b, head_b, VOCABz);
#undef CONV

  {
    size_t t1 = (size_t)NLz * 3 * Cz * Cz;
    pack_qkv_t<<<(t1 + 255) / 256, 256, 0, stream>>>(r_qw, r_kw, r_vw, wqkv_t, flag);
    size_t t2 = (size_t)NLz * Cz * Cz;
    transpose_w<<<(t2 + 255) / 256, 256, 0, stream>>>(r_proj_w, proj_t, NLz, Cz, Cz, flag);
    size_t t3 = (size_t)NLz * Cz * 4 * Cz;
    transpose_w<<<(t3 + 255) / 256, 256, 0, stream>>>(r_ff1_w, ff1_t, NLz, Cz, 4 * Cz, flag);
    transpose_w<<<(t3 + 255) / 256, 256, 0, stream>>>(r_ff2_w, ff2_t, NLz, 4 * Cz, Cz, flag);
    size_t t4 = (size_t)Cz * VOCABz;
    transpose_w<<<(t4 + 255) / 256, 256, 0, stream>>>(r_head_w, head_t, 1, Cz, VOCABz, flag);
  }

  embed_kernel<<<NTOK, 256, 0, stream>>>(idx, tok_emb, pe_w, pe_b, vlut, x_res);

  for (int l = 0; l < NLz; l++) {
    ln_kernel<<<NTOK, 256, 0, stream>>>(x_res, ln1_g + l * Cz, ln1_b + l * Cz, h);
    gemm_mfma<<<dim3(3 * Cz / 128, NTOK / 128), 256, 0, stream>>>(
        h, wqkv_t + (size_t)l * 3 * Cz * Cz, nullptr, nullptr, qkv,
        NTOK, 3 * Cz, Cz, 0, flag);
    transpose_v<<<dim3(Tz / 64, Bz * NHz), 256, 0, stream>>>(qkv, Vt);
    attn_flash<<<dim3(Tz / 64, Bz * NHz), 256, 0, stream>>>(qkv, Vt, rbias, attn);
    gemm_mfma<<<dim3(Cz / 128, NTOK / 128), 256, 0, stream>>>(
        attn, proj_t + (size_t)l * Cz * Cz, proj_b + l * Cz, x_res, nullptr,
        NTOK, Cz, Cz, 2, flag);
    ln_kernel<<<NTOK, 256, 0, stream>>>(x_res, ln2_g + l * Cz, ln2_b + l * Cz, h);
    gemm_mfma<<<dim3(4 * Cz / 128, NTOK / 128), 256, 0, stream>>>(
        h, ff1_t + (size_t)l * 4 * Cz * Cz, ff1_b + (size_t)l * 4 * Cz, nullptr,
        ffm, NTOK, 4 * Cz, Cz, 1, flag);
    gemm_mfma<<<dim3(Cz / 128, NTOK / 128), 256, 0, stream>>>(
        ffm, ff2_t + (size_t)l * 4 * Cz * Cz, ff2_b + l * Cz, x_res, nullptr,
        NTOK, Cz, 4 * Cz, 2, flag);
  }
  ln_kernel<<<NTOK, 256, 0, stream>>>(x_res, lnf_g, lnf_b, h);
  gemm_mfma<<<dim3(1, NTOK / 128), 256, 0, stream>>>(
      h, head_t, head_b, nullptr, d_out, NTOK, VOCABz, Cz, 3, flag);
}

// Round 4
// 1875.318 us; speedup vs baseline: 6.1282x; 1.2253x over previous
//
#include <hip/hip_runtime.h>
#include <hip/hip_bf16.h>
#include <math.h>

// SpectralGPT forward on MI355X. B=4 T=1024 C=768 NH=12 HS=64 NL=6 VOCAB=128.
// Round 4: GEMM rebuilt on global_load_lds (direct-to-LDS DMA), double-buffered
// LDS with ONE barrier per K-slab, XOR-swizzled LDS layout giving conflict-free
// ds_read_b128 fragment reads. Coalesced LDS-tiled weight transposes.
// fp32 residual stream; bf16 activations; runtime input-dtype detect kept.

#define Bz 4
#define Tz 1024
#define Cz 768
#define NHz 12
#define HSz 64
#define NLz 6
#define VOCABz 128
#define NTOK (Bz * Tz)  // 4096

typedef __hip_bfloat16 bf16;
typedef __attribute__((ext_vector_type(8))) __bf16 bf16x8;
typedef __attribute__((ext_vector_type(4))) float f32x4;

#define MFMA16(a, b, c) __builtin_amdgcn_mfma_f32_16x16x32_bf16(a, b, c, 0, 0, 0)

__device__ __forceinline__ float bf2f(bf16 x) { return __bfloat162float(x); }
__device__ __forceinline__ bf16 f2bf(float x) { return __float2bfloat16(x); }
__device__ __forceinline__ float ldx(const void* p, size_t i, int f) {
  return f ? bf2f(((const bf16*)p)[i]) : ((const float*)p)[i];
}
// async global->LDS, 16B per lane. lds base must be wave-uniform; HW writes
// lane i at lds + i*16.
__device__ __forceinline__ void async16(const bf16* g, bf16* l) {
  __builtin_amdgcn_global_load_lds(
      (const __attribute__((address_space(1))) unsigned int*)g,
      (__attribute__((address_space(3))) unsigned int*)l, 16, 0, 0);
}

// -------------------------------------------------------------- dtype detect
__global__ void detect_kernel(const void* g1, int* flag) {
  if (threadIdx.x == 0) {
    const unsigned short* p = (const unsigned short*)g1;
    int cnt = 0;
    for (int i = 0; i < 64; i++) cnt += (p[i] == 0x3F80u) ? 1 : 0;
    *flag = (cnt >= 60) ? 1 : 0;
  }
}

// ------------------------------------------------------------- convert->bf16
__global__ __launch_bounds__(256) void convert_kernel(
    const void* __restrict__ src, bf16* __restrict__ dst, int n,
    const int* __restrict__ flagp) {
  int f = *flagp;
  int i = blockIdx.x * 256 + threadIdx.x;
  if (i >= n) return;
  dst[i] = f ? ((const bf16*)src)[i] : f2bf(((const float*)src)[i]);
}

// -------------------------------------------- tiled transpose (coalesced)
// src: logical [R][C] (dtype per flag), matrix z at z*s_mat elems.
// dst: bf16 [C][R] at d_base + (z/hmod)*d_l + (z%hmod)*d_h elems.
__global__ __launch_bounds__(256) void transpose_tiled(
    const void* __restrict__ src, bf16* __restrict__ dst, int R, int C,
    size_t s_mat, size_t d_base, size_t d_l, size_t d_h, int hmod,
    const int* __restrict__ flagp) {
  __shared__ bf16 t[64][65];
  int f = *flagp;
  int c0 = blockIdx.x * 64, r0 = blockIdx.y * 64;
  int z = blockIdx.z;
  size_t so = (size_t)z * s_mat;
  size_t dofs = d_base + (size_t)(z / hmod) * d_l + (size_t)(z % hmod) * d_h;
  int tr = threadIdx.x >> 2;
  int tc = (threadIdx.x & 3) * 16;
  size_t sbase = so + (size_t)(r0 + tr) * C + c0 + tc;
#pragma unroll
  for (int u = 0; u < 16; u++) t[tr][tc + u] = f2bf(ldx(src, sbase + u, f));
  __syncthreads();
  int wc = threadIdx.x >> 2;
  int wr = (threadIdx.x & 3) * 16;
  bf16* dp = dst + dofs + (size_t)(c0 + wc) * R + r0 + wr;
#pragma unroll
  for (int u = 0; u < 16; u++) dp[u] = t[wr + u][wc];
}

// ---------------------------------------------------------------- embedding
__global__ __launch_bounds__(256) void embed_kernel(
    const int* __restrict__ idx, const bf16* __restrict__ tok_emb,
    const bf16* __restrict__ pe_w, const bf16* __restrict__ pe_b,
    const bf16* __restrict__ vlut, float* __restrict__ x_res) {
  int row = blockIdx.x;
  int t = row % Tz;
  int tok = idx[row];
  float vl[10];
#pragma unroll
  for (int p = 0; p < 10; p++) vl[p] = bf2f(vlut[t * 10 + p]);
  for (int c = threadIdx.x; c < Cz; c += 256) {
    float acc = bf2f(tok_emb[(size_t)tok * Cz + c]) + bf2f(pe_b[c]);
#pragma unroll
    for (int p = 0; p < 10; p++) acc += vl[p] * bf2f(pe_w[p * Cz + c]);
    x_res[(size_t)row * Cz + c] = acc;
  }
}

// ---------------------------------------------------------------- layernorm
__global__ __launch_bounds__(256) void ln_kernel(
    const float* __restrict__ x, const bf16* __restrict__ g,
    const bf16* __restrict__ b, bf16* __restrict__ out) {
  __shared__ float r1[4], r2[4];
  int row = blockIdx.x, tid = threadIdx.x;
  const float* xr = x + (size_t)row * Cz;
  float v0 = xr[tid], v1 = xr[tid + 256], v2 = xr[tid + 512];
  float s1 = v0 + v1 + v2, s2 = v0 * v0 + v1 * v1 + v2 * v2;
#pragma unroll
  for (int off = 32; off > 0; off >>= 1) {
    s1 += __shfl_down(s1, off);
    s2 += __shfl_down(s2, off);
  }
  int lane = tid & 63, wid = tid >> 6;
  if (lane == 0) { r1[wid] = s1; r2[wid] = s2; }
  __syncthreads();
  s1 = r1[0] + r1[1] + r1[2] + r1[3];
  s2 = r2[0] + r2[1] + r2[2] + r2[3];
  float m = s1 * (1.0f / Cz);
  float var = s2 * (1.0f / Cz) - m * m;
  float inv = rsqrtf(var + 1e-5f);
  bf16* orow = out + (size_t)row * Cz;
  orow[tid] = f2bf((v0 - m) * inv * bf2f(g[tid]) + bf2f(b[tid]));
  orow[tid + 256] = f2bf((v1 - m) * inv * bf2f(g[tid + 256]) + bf2f(b[tid + 256]));
  orow[tid + 512] = f2bf((v2 - m) * inv * bf2f(g[tid + 512]) + bf2f(b[tid + 512]));
}

// ---------------------------------------------------------------- MFMA GEMM
// C[M,N] = A[M,K](bf16 rowmajor) x W (bf16, pre-transposed [N][K]) + bias
// 128x128 tile, BK=32, double-buffered LDS filled by global_load_lds.
// Swizzled LDS layout (per 128x32 half, unpadded 8KB):
//   logical (row, colblk cb of 8 elems): rp=row>>1, pl=((row&1)<<2)|cb,
//   pp = pl ^ (rp&7), byte offset = rp*128 + pp*16.
// -> ds_read_b128 fragment reads: every aligned 8-lane group covers all 32
//    banks (conflict-free); global_load_lds lane->16B slot bijection holds.
// mode 0: out=bf16(r)  1: out=bf16(gelu(r))  2: resid += r  3: per-flag out
__global__ __launch_bounds__(256) void gemm_mfma(
    const bf16* __restrict__ A, const bf16* __restrict__ Wt,
    const bf16* __restrict__ bias, float* __restrict__ resid,
    void* __restrict__ out, int M, int N, int K, int mode,
    const int* __restrict__ flagp) {
  __shared__ bf16 lds[2][2][4096];  // [buf][A/B][128x32 swizzled]
  int tid = threadIdx.x;
  int lane = tid & 63, w = tid >> 6;
  int wm = (w >> 1) * 64, wn = (w & 1) * 64;
  int q = lane >> 4, ln = lane & 15;
  int m0 = blockIdx.y * 128, n0 = blockIdx.x * 128;

  // staging decode: inst p covers bytes [w*2048+p*1024, +1024) of the 8KB half
  const bf16* gA[2];
  const bf16* gB[2];
#pragma unroll
  for (int p = 0; p < 2; p++) {
    int o = w * 2048 + p * 1024 + lane * 16;
    int rp = o >> 7, pp = (o >> 4) & 7;
    int pl = pp ^ (rp & 7);
    int row = rp * 2 + (pl >> 2);
    int cb = pl & 3;
    gA[p] = A + (size_t)(m0 + row) * K + cb * 8;
    gB[p] = Wt + (size_t)(n0 + row) * K + cb * 8;
  }
  // fragment read offsets (elems): row = {wm|wn}+i*16+ln, colblk q
  int ppf = (((ln & 1) << 2) | q) ^ (ln >> 1);
  int aoff = wm * 32 + (ln >> 1) * 64 + ppf * 8;
  int boff = wn * 32 + (ln >> 1) * 64 + ppf * 8;

  f32x4 acc[4][4] = {};
  // prefetch slab 0 into buf 0
#pragma unroll
  for (int p = 0; p < 2; p++) {
    async16(gA[p], &lds[0][0][w * 1024 + p * 512]);
    async16(gB[p], &lds[0][1][w * 1024 + p * 512]);
  }
  int cur = 0;
  for (int k0 = 0; k0 < K; k0 += 32) {
    __syncthreads();  // drains vmcnt -> buf[cur] ready
    if (k0 + 32 < K) {
      int nxt = cur ^ 1;
#pragma unroll
      for (int p = 0; p < 2; p++) {
        async16(gA[p] + k0 + 32, &lds[nxt][0][w * 1024 + p * 512]);
        async16(gB[p] + k0 + 32, &lds[nxt][1][w * 1024 + p * 512]);
      }
    }
    bf16x8 af[4], bfr[4];
#pragma unroll
    for (int i = 0; i < 4; i++)
      af[i] = *(const bf16x8*)&lds[cur][0][aoff + i * 512];
#pragma unroll
    for (int j = 0; j < 4; j++)
      bfr[j] = *(const bf16x8*)&lds[cur][1][boff + j * 512];
#pragma unroll
    for (int i = 0; i < 4; i++)
#pragma unroll
      for (int j = 0; j < 4; j++)
        acc[i][j] = MFMA16(af[i], bfr[j], acc[i][j]);
    cur ^= 1;
  }
  int f = *flagp;
  float bj[4];
#pragma unroll
  for (int j = 0; j < 4; j++)
    bj[j] = bias ? bf2f(bias[n0 + wn + j * 16 + ln]) : 0.0f;
#pragma unroll
  for (int i = 0; i < 4; i++) {
#pragma unroll
    for (int j = 0; j < 4; j++) {
      int col = n0 + wn + j * 16 + ln;
#pragma unroll
      for (int r = 0; r < 4; r++) {
        int row = m0 + wm + i * 16 + q * 4 + r;
        float v = acc[i][j][r] + bj[j];
        size_t oi = (size_t)row * N + col;
        if (mode == 0) {
          ((bf16*)out)[oi] = f2bf(v);
        } else if (mode == 1) {
          ((bf16*)out)[oi] = f2bf(v * 0.5f * (1.0f + erff(v * 0.70710678118f)));
        } else if (mode == 2) {
          resid[oi] += v;
        } else {
          if (f) ((bf16*)out)[oi] = f2bf(v);
          else ((float*)out)[oi] = v;
        }
      }
    }
  }
}

// --------------------------------------------- V transpose: qkv -> Vt[bh][d][s]
#define ATS 72
__global__ __launch_bounds__(256) void transpose_v(
    const bf16* __restrict__ qkv, bf16* __restrict__ Vt) {
  __shared__ bf16 tile[64][ATS];
  int tid = threadIdx.x;
  int s0 = blockIdx.x * 64, bh = blockIdx.y;
  int b = bh / NHz, h = bh % NHz;
  int row = tid >> 2, c0 = (tid & 3) * 16;
  const bf16* src = qkv + ((size_t)(b * Tz + s0 + row)) * (3 * Cz) + 2 * Cz + h * HSz + c0;
  *(uint4*)&tile[row][c0] = *(const uint4*)src;
  *(uint4*)&tile[row][c0 + 8] = *(const uint4*)(src + 8);
  __syncthreads();
  int d = tid >> 2, sc0 = (tid & 3) * 16;
  unsigned int u[8];
#pragma unroll
  for (int m = 0; m < 8; m++) {
    unsigned int lo = *(const unsigned short*)&tile[sc0 + 2 * m][d];
    unsigned int hi = *(const unsigned short*)&tile[sc0 + 2 * m + 1][d];
    u[m] = lo | (hi << 16);
  }
  bf16* dst = Vt + ((size_t)bh * HSz + d) * Tz + s0 + sc0;
  ((uint4*)dst)[0] = make_uint4(u[0], u[1], u[2], u[3]);
  ((uint4*)dst)[1] = make_uint4(u[4], u[5], u[6], u[7]);
}

// ------------------------------------------------------- flash MFMA attention
__global__ __launch_bounds__(256) void attn_flash(
    const bf16* __restrict__ qkv, const bf16* __restrict__ Vt,
    const bf16* __restrict__ rbias, bf16* __restrict__ attn_out) {
  __shared__ bf16 Qs[64][ATS];
  __shared__ bf16 Ks[64][ATS];
  __shared__ bf16 Vs[64][ATS];
  __shared__ bf16 Ps[4][16][ATS];
  int tid = threadIdx.x;
  int lane = tid & 63, w = tid >> 6;
  int q = lane >> 4, ln = lane & 15;
  int t0 = blockIdx.x * 64, bh = blockIdx.y;
  int b = bh / NHz, h = bh % NHz;
  const float scale = 0.03608439182435161f;  // C^-0.5 = 1/sqrt(768)
  int srow = tid >> 2, sc = (tid & 3) * 16;
  {
    const bf16* src = qkv + ((size_t)(b * Tz + t0 + srow)) * (3 * Cz) + h * HSz + sc;
    *(uint4*)&Qs[srow][sc] = *(const uint4*)src;
    *(uint4*)&Qs[srow][sc + 8] = *(const uint4*)(src + 8);
  }
  float mrow[4], lrow[4];
  f32x4 Oacc[4] = {};
#pragma unroll
  for (int r = 0; r < 4; r++) { mrow[r] = -3.0e38f; lrow[r] = 0.0f; }
  int t_base = t0 + w * 16 + q * 4;

  for (int s0 = 0; s0 <= t0 + 63; s0 += 64) {
    __syncthreads();
    {
      const bf16* ksrc = qkv + ((size_t)(b * Tz + s0 + srow)) * (3 * Cz) + Cz + h * HSz + sc;
      *(uint4*)&Ks[srow][sc] = *(const uint4*)ksrc;
      *(uint4*)&Ks[srow][sc + 8] = *(const uint4*)(ksrc + 8);
      const bf16* vsrc = Vt + ((size_t)bh * HSz + srow) * Tz + s0 + sc;
      *(uint4*)&Vs[srow][sc] = *(const uint4*)vsrc;
      *(uint4*)&Vs[srow][sc + 8] = *(const uint4*)(vsrc + 8);
    }
    __syncthreads();
    f32x4 sacc[4] = {};
#pragma unroll
    for (int ks = 0; ks < 64; ks += 32) {
      bf16x8 aq = *(const bf16x8*)&Qs[w * 16 + ln][ks + q * 8];
#pragma unroll
      for (int j = 0; j < 4; j++) {
        bf16x8 bk = *(const bf16x8*)&Ks[j * 16 + ln][ks + q * 8];
        sacc[j] = MFMA16(aq, bk, sacc[j]);
      }
    }
    float sval[4][4];
#pragma unroll
    for (int j = 0; j < 4; j++) {
      int s_col = s0 + j * 16 + ln;
#pragma unroll
      for (int r = 0; r < 4; r++) {
        int t_row = t_base + r;
        float rb = bf2f(rbias[(size_t)t_row * Tz + s_col]);
        float v = sacc[j][r] * scale + rb;
        bool ok = (s_col <= t_row) && ((rb > 0.0f) || (s_col == t_row));
        sval[j][r] = ok ? v : -3.0e38f;
      }
    }
    float rmax[4];
#pragma unroll
    for (int r = 0; r < 4; r++)
      rmax[r] = fmaxf(fmaxf(sval[0][r], sval[1][r]), fmaxf(sval[2][r], sval[3][r]));
#pragma unroll
    for (int msk = 8; msk >= 1; msk >>= 1)
#pragma unroll
      for (int r = 0; r < 4; r++)
        rmax[r] = fmaxf(rmax[r], __shfl_xor(rmax[r], msk));
    float nm[4], nme[4], alpha[4];
#pragma unroll
    for (int r = 0; r < 4; r++) {
      nm[r] = fmaxf(mrow[r], rmax[r]);
      nme[r] = (nm[r] < -1.0e37f) ? 0.0f : nm[r];
      alpha[r] = (mrow[r] < -1.0e37f) ? 0.0f : __expf(mrow[r] - nm[r]);
      mrow[r] = nm[r];
    }
    float pf[4][4];
    float psum[4] = {0.f, 0.f, 0.f, 0.f};
#pragma unroll
    for (int j = 0; j < 4; j++)
#pragma unroll
      for (int r = 0; r < 4; r++) {
        float p = __expf(sval[j][r] - nme[r]);
        pf[j][r] = p;
        psum[r] += p;
      }
#pragma unroll
    for (int msk = 8; msk >= 1; msk >>= 1)
#pragma unroll
      for (int r = 0; r < 4; r++) psum[r] += __shfl_xor(psum[r], msk);
#pragma unroll
    for (int r = 0; r < 4; r++) lrow[r] = alpha[r] * lrow[r] + psum[r];
#pragma unroll
    for (int jd = 0; jd < 4; jd++)
#pragma unroll
      for (int r = 0; r < 4; r++) Oacc[jd][r] *= alpha[r];
#pragma unroll
    for (int j = 0; j < 4; j++)
#pragma unroll
      for (int r = 0; r < 4; r++)
        Ps[w][q * 4 + r][j * 16 + ln] = f2bf(pf[j][r]);
#pragma unroll
    for (int ks = 0; ks < 64; ks += 32) {
      bf16x8 pa = *(const bf16x8*)&Ps[w][ln][ks + q * 8];
#pragma unroll
      for (int jd = 0; jd < 4; jd++) {
        bf16x8 vb = *(const bf16x8*)&Vs[jd * 16 + ln][ks + q * 8];
        Oacc[jd] = MFMA16(pa, vb, Oacc[jd]);
      }
    }
  }
#pragma unroll
  for (int r = 0; r < 4; r++) {
    float inv = 1.0f / lrow[r];
    int t_row = t_base + r;
#pragma unroll
    for (int jd = 0; jd < 4; jd++) {
      attn_out[(size_t)(b * Tz + t_row) * Cz + h * HSz + jd * 16 + ln] =
          f2bf(Oacc[jd][r] * inv);
    }
  }
}

// ---------------------------------------------------------------- launcher
extern "C" void kernel_launch(void* const* d_in, const int* in_sizes, int n_in,
                              void* d_out, int out_size, void* d_ws, size_t ws_size,
                              hipStream_t stream) {
  const int* idx = (const int*)d_in[0];
  int p0 = 7;
  if (n_in == 23) p0 = 6;
  else if (in_sizes[6] != Tz * Tz) p0 = 6;

  const void* r_tok_emb = d_in[1];
  const void* r_pe_w = d_in[2];
  const void* r_pe_b = d_in[3];
  const void* r_vlut = d_in[4];
  const void* r_rbias = d_in[5];
  const void* r_ln1_g = d_in[p0 + 0];
  const void* r_ln1_b = d_in[p0 + 1];
  const void* r_qw = d_in[p0 + 2];
  const void* r_kw = d_in[p0 + 3];
  const void* r_vw = d_in[p0 + 4];
  const void* r_proj_w = d_in[p0 + 5];
  const void* r_proj_b = d_in[p0 + 6];
  const void* r_ln2_g = d_in[p0 + 7];
  const void* r_ln2_b = d_in[p0 + 8];
  const void* r_ff1_w = d_in[p0 + 9];
  const void* r_ff1_b = d_in[p0 + 10];
  const void* r_ff2_w = d_in[p0 + 11];
  const void* r_ff2_b = d_in[p0 + 12];
  const void* r_lnf_g = d_in[p0 + 13];
  const void* r_lnf_b = d_in[p0 + 14];
  const void* r_head_w = d_in[p0 + 15];
  const void* r_head_b = d_in[p0 + 16];

  char* wsp = (char*)d_ws;
  auto alloc = [&](size_t bytes) {
    char* p = wsp;
    wsp += (bytes + 255) & ~(size_t)255;
    return (void*)p;
  };
  int* flag = (int*)alloc(256);
  float* x_res = (float*)alloc((size_t)NTOK * Cz * 4);
  bf16* h = (bf16*)alloc((size_t)NTOK * Cz * 2);
  bf16* qkv = (bf16*)alloc((size_t)NTOK * 3 * Cz * 2);
  bf16* attn = (bf16*)alloc((size_t)NTOK * Cz * 2);
  bf16* ffm = (bf16*)alloc((size_t)NTOK * 4 * Cz * 2);
  bf16* Vt = (bf16*)alloc((size_t)Bz * NHz * HSz * Tz * 2);
  bf16* wqkv_t = (bf16*)alloc((size_t)NLz * 3 * Cz * Cz * 2);
  bf16* proj_t = (bf16*)alloc((size_t)NLz * Cz * Cz * 2);
  bf16* ff1_t = (bf16*)alloc((size_t)NLz * 4 * Cz * Cz * 2);
  bf16* ff2_t = (bf16*)alloc((size_t)NLz * 4 * Cz * Cz * 2);
  bf16* head_t = (bf16*)alloc((size_t)VOCABz * Cz * 2);
  bf16* tok_emb = (bf16*)alloc((size_t)VOCABz * Cz * 2);
  bf16* pe_w = (bf16*)alloc(10 * Cz * 2);
  bf16* pe_b = (bf16*)alloc(Cz * 2);
  bf16* vlut = (bf16*)alloc(Tz * 10 * 2);
  bf16* rbias = (bf16*)alloc((size_t)Tz * Tz * 2);
  bf16* ln1_g = (bf16*)alloc(NLz * Cz * 2);
  bf16* ln1_b = (bf16*)alloc(NLz * Cz * 2);
  bf16* proj_b = (bf16*)alloc(NLz * Cz * 2);
  bf16* ln2_g = (bf16*)alloc(NLz * Cz * 2);
  bf16* ln2_b = (bf16*)alloc(NLz * Cz * 2);
  bf16* ff1_b = (bf16*)alloc(NLz * 4 * Cz * 2);
  bf16* ff2_b = (bf16*)alloc(NLz * Cz * 2);
  bf16* lnf_g = (bf16*)alloc(Cz * 2);
  bf16* lnf_b = (bf16*)alloc(Cz * 2);
  bf16* head_b = (bf16*)alloc(VOCABz * 2);

  detect_kernel<<<1, 64, 0, stream>>>(r_ln1_g, flag);

#define CONV(src, dst, n) \
  convert_kernel<<<((n) + 255) / 256, 256, 0, stream>>>(src, dst, n, flag)
  CONV(r_tok_emb, tok_emb, VOCABz * Cz);
  CONV(r_pe_w, pe_w, 10 * Cz);
  CONV(r_pe_b, pe_b, Cz);
  CONV(r_vlut, vlut, Tz * 10);
  CONV(r_rbias, rbias, Tz * Tz);
  CONV(r_ln1_g, ln1_g, NLz * Cz);
  CONV(r_ln1_b, ln1_b, NLz * Cz);
  CONV(r_proj_b, proj_b, NLz * Cz);
  CONV(r_ln2_g, ln2_g, NLz * Cz);
  CONV(r_ln2_b, ln2_b, NLz * Cz);
  CONV(r_ff1_b, ff1_b, NLz * 4 * Cz);
  CONV(r_ff2_b, ff2_b, NLz * Cz);
  CONV(r_lnf_g, lnf_g, Cz);
  CONV(r_lnf_b, lnf_b, Cz);
  CONV(r_head_b, head_b, VOCABz);
#undef CONV

  // weight transposes (coalesced, LDS-tiled)
  // qkv: per (l,h) matrices [768][64] -> wqkv_t[l][g*768+h*64+d][k]
  for (int g = 0; g < 3; g++) {
    const void* src = (g == 0) ? r_qw : (g == 1) ? r_kw : r_vw;
    transpose_tiled<<<dim3(1, Cz / 64, NLz * NHz), 256, 0, stream>>>(
        src, wqkv_t, Cz, HSz, (size_t)Cz * HSz,
        (size_t)g * Cz * Cz, (size_t)3 * Cz * Cz, (size_t)HSz * Cz, NHz, flag);
  }
  transpose_tiled<<<dim3(Cz / 64, Cz / 64, NLz), 256, 0, stream>>>(
      r_proj_w, proj_t, Cz, Cz, (size_t)Cz * Cz, 0, (size_t)Cz * Cz, 0, 1, flag);
  transpose_tiled<<<dim3(4 * Cz / 64, Cz / 64, NLz), 256, 0, stream>>>(
      r_ff1_w, ff1_t, Cz, 4 * Cz, (size_t)4 * Cz * Cz, 0, (size_t)4 * Cz * Cz, 0, 1, flag);
  transpose_tiled<<<dim3(Cz / 64, 4 * Cz / 64, NLz), 256, 0, stream>>>(
      r_ff2_w, ff2_t, 4 * Cz, Cz, (size_t)4 * Cz * Cz, 0, (size_t)4 * Cz * Cz, 0, 1, flag);
  transpose_tiled<<<dim3(VOCABz / 64, Cz / 64, 1), 256, 0, stream>>>(
      r_head_w, head_t, Cz, VOCABz, 0, 0, 0, 0, 1, flag);

  embed_kernel<<<NTOK, 256, 0, stream>>>(idx, tok_emb, pe_w, pe_b, vlut, x_res);

  for (int l = 0; l < NLz; l++) {
    ln_kernel<<<NTOK, 256, 0, stream>>>(x_res, ln1_g + l * Cz, ln1_b + l * Cz, h);
    gemm_mfma<<<dim3(3 * Cz / 128, NTOK / 128), 256, 0, stream>>>(
        h, wqkv_t + (size_t)l * 3 * Cz * Cz, nullptr, nullptr, qkv,
        NTOK, 3 * Cz, Cz, 0, flag);
    transpose_v<<<dim3(Tz / 64, Bz * NHz), 256, 0, stream>>>(qkv, Vt);
    attn_flash<<<dim3(Tz / 64, Bz * NHz), 256, 0, stream>>>(qkv, Vt, rbias, attn);
    gemm_mfma<<<dim3(Cz / 128, NTOK / 128), 256, 0, stream>>>(
        attn, proj_t + (size_t)l * Cz * Cz, proj_b + l * Cz, x_res, nullptr,
        NTOK, Cz, Cz, 2, flag);
    ln_kernel<<<NTOK, 256, 0, stream>>>(x_res, ln2_g + l * Cz, ln2_b + l * Cz, h);
    gemm_mfma<<<dim3(4 * Cz / 128, NTOK / 128), 256, 0, stream>>>(
        h, ff1_t + (size_t)l * 4 * Cz * Cz, ff1_b + (size_t)l * 4 * Cz, nullptr,
        ffm, NTOK, 4 * Cz, Cz, 1, flag);
    gemm_mfma<<<dim3(Cz / 128, NTOK / 128), 256, 0, stream>>>(
        ffm, ff2_t + (size_t)l * 4 * Cz * Cz, ff2_b + l * Cz, x_res, nullptr,
        NTOK, Cz, 4 * Cz, 2, flag);
  }
  ln_kernel<<<NTOK, 256, 0, stream>>>(x_res, lnf_g, lnf_b, h);
  gemm_mfma<<<dim3(VOCABz / 128, NTOK / 128), 256, 0, stream>>>(
      h, head_t, head_b, nullptr, d_out, NTOK, VOCABz, Cz, 3, flag);
}